// Round 9
// baseline (364.068 us; speedup 1.0000x reference)
//
#include <hip/hip_runtime.h>
#include <hip/hip_bf16.h>
#include <cstddef>

// Problem constants (match reference).
#define NQ 8192
#define DD 1024

typedef __attribute__((ext_vector_type(8))) short s8v;     // 8 bf16 (4 VGPR)
typedef __attribute__((ext_vector_type(8))) int i8v;       // 32 fp8 bytes (8 VGPR)
typedef __attribute__((ext_vector_type(4))) float f32x4;   // 16x16 C/D frag
typedef __attribute__((ext_vector_type(16))) float f32x16; // 32x32 C/D frag

typedef const __attribute__((address_space(1))) unsigned int* gptr_t;
typedef __attribute__((address_space(3))) unsigned int* lptr_t;

#define SCALE_1_16 0x7B7B7B7Bu  // E8M0 123 = 2^-4 in every byte

__device__ inline unsigned short f2bf(float f) {
  union { float f; unsigned u; } v; v.f = f;
  unsigned r = (v.u + 0x7FFFu + ((v.u >> 16) & 1u)) >> 16;  // RNE
  return (unsigned short)r;
}
__device__ inline float bits2f(unsigned u) {
  union { unsigned u; float f; } v; v.u = u;
  return v.f;
}

// f32 -> OCP e4m3 bits, RNE, clamp to +-448.
__device__ inline unsigned char f2e4m3(float x) {
  union { float f; unsigned u; } v; v.f = x;
  const unsigned s = (v.u >> 31) << 7;
  unsigned au = v.u & 0x7FFFFFFFu;
  if (au > 0x43E00000u) au = 0x43E00000u;  // clamp |x| to 448.0
  if (au >= 0x3C800000u) {                 // |x| >= 2^-6: e4m3 normal
    const unsigned rounded = au + 0x7FFFFu + ((au >> 20) & 1u);  // RNE @ 3 mant
    const unsigned e8 = ((rounded >> 23) & 0xFF) - 120u;         // -127+7
    const unsigned m8 = (rounded >> 20) & 7u;
    return (unsigned char)(s | (e8 << 3) | m8);
  } else {                                 // subnormal
    union { unsigned u; float f; } a; a.u = au;
    const unsigned q = (unsigned)rintf(a.f * 512.0f);  // 0..8
    return (unsigned char)(s | q);
  }
}

// Register-only combine of two 16-B LDS loads into one fp8 MFMA operand.
__device__ inline i8v make_i8v(int4 a, int4 b) {
  i8v v;
  v[0] = a.x; v[1] = a.y; v[2] = a.z; v[3] = a.w;
  v[4] = b.x; v[5] = b.y; v[6] = b.z; v[7] = b.w;
  return v;
}

// ---------------------------------------------------------------------------
// Double-buffered m97-style bf16 MFMA loop: C(128x128) += A(128xK) @ B(128xK)^T.
// stage(t+1) ISSUED before compute(t); one vmcnt(0)+barrier per K-step.
// Proven round-6: pv 143 -> 128.6 us, MfmaUtil 48%.
// XOR-swizzled 16-B chunks, 0 bank conflicts (verified round-0).
// ---------------------------------------------------------------------------
template <int KDIM, int ASTR, int BSTR>
__device__ inline void mfma_core_db(const unsigned short* __restrict__ A,
                                    const unsigned short* __restrict__ B,
                                    int i0, int j0, int tid,
                                    unsigned short* __restrict__ As0,
                                    unsigned short* __restrict__ As1,
                                    unsigned short* __restrict__ Bs0,
                                    unsigned short* __restrict__ Bs1,
                                    f32x4 (&acc)[4][4]) {
  const int lane = tid & 63;
  const int w = tid >> 6;
  const int wr = (w >> 1) * 64;
  const int wc = (w & 1) * 64;
  const int l16 = lane & 15;
  const int lq = lane >> 4;
  const int srow = lane >> 3;                          // 0..7
  const int scol = (((lane & 7) ^ (srow & 7)) * 8);    // swizzled 16-B chunk

  auto stage = [&](unsigned short* dA, unsigned short* dB, int kk) {
#pragma unroll
    for (int t = 0; t < 4; t++) {
      const int r0 = w * 32 + t * 8;
      const unsigned short* g = &A[(size_t)(i0 + r0 + srow) * ASTR + kk + scol];
      __builtin_amdgcn_global_load_lds((gptr_t)(const void*)g,
                                       (lptr_t)(void*)&dA[r0 * 64], 16, 0, 0);
    }
#pragma unroll
    for (int t = 0; t < 4; t++) {
      const int r0 = w * 32 + t * 8;
      const unsigned short* g = &B[(size_t)(j0 + r0 + srow) * BSTR + kk + scol];
      __builtin_amdgcn_global_load_lds((gptr_t)(const void*)g,
                                       (lptr_t)(void*)&dB[r0 * 64], 16, 0, 0);
    }
  };

  stage(As0, Bs0, 0);
  asm volatile("s_waitcnt vmcnt(0)" ::: "memory");
  __syncthreads();

  const int h = l16 & 7;
  unsigned short* curA = As0;
  unsigned short* curB = Bs0;
  unsigned short* nxtA = As1;
  unsigned short* nxtB = Bs1;
#pragma unroll 1
  for (int t = 0; t < KDIM / 64; t++) {
    if (t < KDIM / 64 - 1) stage(nxtA, nxtB, (t + 1) * 64);  // fly over compute
    s8v af[4][2], bf[4][2];
#pragma unroll
    for (int q = 0; q < 4; q++)
#pragma unroll
      for (int s = 0; s < 2; s++) {
        const int ch = ((s * 4 + lq) ^ h) * 8;  // swizzled chunk offset
        af[q][s] = *(const s8v*)&curA[(wr + 16 * q + l16) * 64 + ch];
        bf[q][s] = *(const s8v*)&curB[(wc + 16 * q + l16) * 64 + ch];
      }
#pragma unroll
    for (int s = 0; s < 2; s++)
#pragma unroll
      for (int a = 0; a < 4; a++)
#pragma unroll
        for (int b = 0; b < 4; b++)
          acc[a][b] = __builtin_amdgcn_mfma_f32_16x16x32_bf16(
              af[a][s], bf[b][s], acc[a][b], 0, 0, 0);
    asm volatile("s_waitcnt vmcnt(0)" ::: "memory");  // next buffer landed
    __syncthreads();
    unsigned short* tA = curA; curA = nxtA; nxtA = tA;
    unsigned short* tB = curB; curB = nxtB; nxtB = tB;
  }
}

// ---------------------------------------------------------------------------
// fp32 -> bf16 elementwise.
// ---------------------------------------------------------------------------
__global__ void f32_to_bf16(const float* __restrict__ in,
                            unsigned short* __restrict__ out, int n4) {
  int i = (blockIdx.x * blockDim.x + threadIdx.x);
  if (i < n4) {
    const float4 v = *(const float4*)&in[i * 4];
    ushort4 o;
    o.x = f2bf(v.x); o.y = f2bf(v.y); o.z = f2bf(v.z); o.w = f2bf(v.w);
    *(ushort4*)&out[i * 4] = o;
  }
}

__global__ void zero_f32(float* __restrict__ p, int n) {
  const int i = blockIdx.x * blockDim.x + threadIdx.x;
  if (i < n) p[i] = 0.f;
}

// ---------------------------------------------------------------------------
// fp32 [R][C] -> bf16 [C][R] transpose+convert (32x32 LDS tiles).
// ---------------------------------------------------------------------------
__global__ void transpose_cvt(const float* __restrict__ in,
                              unsigned short* __restrict__ out, int R, int C) {
  __shared__ float t[32][33];
  const int bx = blockIdx.x;
  const int by = blockIdx.y;
  const int x = threadIdx.x & 31;
  const int y = threadIdx.x >> 5;
#pragma unroll
  for (int i = 0; i < 32; i += 8)
    t[y + i][x] = in[(size_t)(by * 32 + y + i) * C + bx * 32 + x];
  __syncthreads();
#pragma unroll
  for (int i = 0; i < 32; i += 8)
    out[(size_t)(bx * 32 + y + i) * R + by * 32 + x] = f2bf(t[x][y + i]);
}

// ---------------------------------------------------------------------------
// Projection GEMM: C[m][n] = sum_k A[m][k] * BT[n][k], bf16 in, K=1024.
// FP8OUT=true writes e4m3(16*value) for the MX qk pass (8 MB output — byte
// stores fine at this size, verified rounds 0-2; xif is L3-resident so no
// partial-sector amplification).
// ---------------------------------------------------------------------------
template <int NST, bool FP8OUT>
__global__ __launch_bounds__(256, 2)
void proj_gemm(const unsigned short* __restrict__ A,
               const unsigned short* __restrict__ BT,
               void* __restrict__ Cout) {
  __shared__ __align__(16) unsigned short As[2][128 * 64];
  __shared__ __align__(16) unsigned short Bs[2][128 * 64];
  const int tid = threadIdx.x;
  const int m0 = blockIdx.y * 128;
  const int n0 = blockIdx.x * 128;

  f32x4 acc[4][4];
#pragma unroll
  for (int a = 0; a < 4; a++)
#pragma unroll
    for (int b = 0; b < 4; b++) acc[a][b] = (f32x4){0.f, 0.f, 0.f, 0.f};

  mfma_core_db<DD, DD, DD>(A, BT, m0, n0, tid, As[0], As[1], Bs[0], Bs[1], acc);

  const int lane = tid & 63;
  const int w = tid >> 6;
  const int wr = (w >> 1) * 64, wc = (w & 1) * 64;
  const int l16 = lane & 15, lq = lane >> 4;
#pragma unroll
  for (int ti = 0; ti < 4; ti++)
#pragma unroll
    for (int r = 0; r < 4; r++) {
      const int row = m0 + wr + 16 * ti + lq * 4 + r;
#pragma unroll
      for (int tj = 0; tj < 4; tj++) {
        const int col = n0 + wc + 16 * tj + l16;
        if (FP8OUT) {
          ((unsigned char*)Cout)[(size_t)row * NST + col] =
              f2e4m3(acc[ti][tj][r] * 16.f);
        } else {
          ((unsigned short*)Cout)[(size_t)row * NST + col] = f2bf(acc[ti][tj][r]);
        }
      }
    }
}

// ---------------------------------------------------------------------------
// Pass 1: P = exp(xi @ xi^T) via MX-scaled fp8 MFMA.
// Round-8: tile widened to 128 x 256 (2 j-tiles per block) — 25% less LDS
// traffic per output, 8 mfma_scale per wave-step (vs 4).  Wave tile 64x128:
// acc[2][4] f32x16 = 128 VGPR -> __launch_bounds__(256,2).
// LDS: A dbuf 2x8 KB + B dbuf 2x16 KB = 48 KB; epilogue overlays lsums
// (33.3 KB) then the bf16 half-tile (32 KB) on the same region.
// Staging/swizzle/read patterns are the proven ones generalized to 256 rows.
// Audited for hang classes (r8 infra failure): no divergent barriers, no OOB,
// full (row,col) coverage, VGPR ~200 < 256 budget.
// ---------------------------------------------------------------------------
__global__ __launch_bounds__(256, 2)
void qk_fp8(const unsigned char* __restrict__ xif,  // [8192][1024] e4m3(16*xi)
            unsigned short* __restrict__ P,         // [8192][8192] bf16 bits
            float* __restrict__ lsum) {             // [8192] fp32 (pre-zeroed)
  __shared__ __align__(16) unsigned char smem[49152];  // 48 KB overlay
  unsigned char* A0 = smem;           // 8 KB  (128 rows x 64 B)
  unsigned char* B0 = smem + 8192;    // 16 KB (256 rows x 64 B)
  unsigned char* A1 = smem + 24576;   // 8 KB
  unsigned char* B1 = smem + 32768;   // 16 KB
  const int tid = threadIdx.x;
  const int lane = tid & 63;
  const int w = tid >> 6;
  const int i0 = blockIdx.y * 128;
  const int j0 = blockIdx.x * 256;

  f32x16 acc[2][4];
#pragma unroll
  for (int a = 0; a < 2; a++)
#pragma unroll
    for (int b = 0; b < 4; b++)
#pragma unroll
      for (int r = 0; r < 16; r++) acc[a][b][r] = 0.f;

  const int srow = lane >> 2;  // 0..15: row within 16-row staging group
  const int slot = lane & 3;   // 16-B chunk slot within the row
  const int kb = lane >> 5;    // frag k-block (0/1)
  const int l31 = lane & 31;

  auto stage = [&](unsigned char* dA, unsigned char* dB, int kk) {
#pragma unroll
    for (int t = 0; t < 2; t++) {     // A: 128 rows, wave stages 32
      const int r = w * 32 + t * 16 + srow;
      const int c = slot ^ ((r >> 1) & 3);  // logical chunk for this slot
      const unsigned char* ga = &xif[(size_t)(i0 + r) * DD + kk + c * 16];
      __builtin_amdgcn_global_load_lds((gptr_t)(const void*)ga,
                                       (lptr_t)(void*)&dA[(w * 32 + t * 16) * 64],
                                       16, 0, 0);
    }
#pragma unroll
    for (int t = 0; t < 4; t++) {     // B: 256 rows, wave stages 64
      const int r = w * 64 + t * 16 + srow;
      const int c = slot ^ ((r >> 1) & 3);
      const unsigned char* gb = &xif[(size_t)(j0 + r) * DD + kk + c * 16];
      __builtin_amdgcn_global_load_lds((gptr_t)(const void*)gb,
                                       (lptr_t)(void*)&dB[(w * 64 + t * 16) * 64],
                                       16, 0, 0);
    }
  };

  stage(A0, B0, 0);
  asm volatile("s_waitcnt vmcnt(0)" ::: "memory");
  __syncthreads();

  unsigned char* curA = A0;
  unsigned char* curB = B0;
  unsigned char* nxtA = A1;
  unsigned char* nxtB = B1;
#pragma unroll 1
  for (int t = 0; t < DD / 64; t++) {
    if (t < DD / 64 - 1) stage(nxtA, nxtB, (t + 1) * 64);  // fly over compute

    i8v af[2], bf[4];
#pragma unroll
    for (int mi = 0; mi < 2; mi++) {
      const int ar = (w >> 1) * 64 + mi * 32 + l31;
      const int sw = (ar >> 1) & 3;
      const int4 q0 = *(const int4*)&curA[ar * 64 + ((2 * kb + 0) ^ sw) * 16];
      const int4 q1 = *(const int4*)&curA[ar * 64 + ((2 * kb + 1) ^ sw) * 16];
      af[mi] = make_i8v(q0, q1);
    }
#pragma unroll
    for (int nj = 0; nj < 4; nj++) {
      const int br = (w & 1) * 128 + nj * 32 + l31;
      const int sw = (br >> 1) & 3;
      const int4 q0 = *(const int4*)&curB[br * 64 + ((2 * kb + 0) ^ sw) * 16];
      const int4 q1 = *(const int4*)&curB[br * 64 + ((2 * kb + 1) ^ sw) * 16];
      bf[nj] = make_i8v(q0, q1);
    }
#pragma unroll
    for (int mi = 0; mi < 2; mi++)
#pragma unroll
      for (int nj = 0; nj < 4; nj++)
        acc[mi][nj] = __builtin_amdgcn_mfma_scale_f32_32x32x64_f8f6f4(
            af[mi], bf[nj], acc[mi][nj], 0 /*cbsz: fp8*/, 0 /*blgp: fp8*/,
            0, SCALE_1_16, 0, SCALE_1_16);

    asm volatile("s_waitcnt vmcnt(0)" ::: "memory");
    __syncthreads();
    unsigned char* tA = curA; curA = nxtA; nxtA = tA;
    unsigned char* tB = curB; curB = nxtB; nxtB = tB;
  }
  // Loop ends with a full barrier: smem staging region is dead from here.

  // 32x32 C layout: row = (reg&3) + 8*(reg>>2) + 4*(lane>>5), col = lane&31.
  // acc[mi][nj] covers row i0+(w>>1)*64+mi*32+..., col j0+(w&1)*128+nj*32+l31.
  const int mbase = (w >> 1) * 64;
  const int rowoff = 4 * (lane >> 5);
  const int cslot = (w & 1) * 32 + l31;  // 64 slots x 4 nj = 256 j per row

  // Phase A: lsums partials (each lane pre-sums its 4 nj), reduce, 1 atomic/row.
  float (*lsums)[65] = (float (*)[65])smem;  // 33.3 KB, padded stride
#pragma unroll
  for (int mi = 0; mi < 2; mi++)
#pragma unroll
    for (int r4 = 0; r4 < 4; r4++)
#pragma unroll
      for (int rr = 0; rr < 4; rr++) {
        const int reg = r4 * 4 + rr;
        const int rl = mbase + mi * 32 + rr + 8 * r4 + rowoff;
        float s = 0.f;
#pragma unroll
        for (int nj = 0; nj < 4; nj++) s += __expf(acc[mi][nj][reg]);
        lsums[rl][cslot] = s;
      }
  __syncthreads();
  if (tid < 128) {
    float s = 0.f;
#pragma unroll
    for (int c = 0; c < 64; c++) s += lsums[tid][c];
    atomicAdd(&lsum[i0 + tid], s);
  }
  __syncthreads();  // lsums reads drained before tile overwrite

  // Phase B: two 128-col halves through the 32 KB tile overlay.
  unsigned short* tile = (unsigned short*)smem;  // [128][128]
#pragma unroll 1
  for (int hh = 0; hh < 2; hh++) {
    if ((w & 1) == hh) {
#pragma unroll
      for (int mi = 0; mi < 2; mi++)
#pragma unroll
        for (int r4 = 0; r4 < 4; r4++)
#pragma unroll
          for (int rr = 0; rr < 4; rr++) {
            const int reg = r4 * 4 + rr;
            const int rl = mbase + mi * 32 + rr + 8 * r4 + rowoff;
#pragma unroll
            for (int nj = 0; nj < 4; nj++)
              tile[rl * 128 + nj * 32 + l31] = f2bf(__expf(acc[mi][nj][reg]));
          }
    }
    __syncthreads();
    {
      const int rr2 = tid >> 4;       // 0..15: row within 16-row group
      const int ch = (tid & 15) * 8;  // 8 shorts = 16 B; 16 lanes = 256 B/row
#pragma unroll
      for (int q = 0; q < 8; q++) {
        const int row = rr2 + q * 16;
        const int4 v = *(const int4*)&tile[row * 128 + ch];
        *(int4*)&P[(size_t)(i0 + row) * NQ + j0 + hh * 128 + ch] = v;
      }
    }
    __syncthreads();  // tile reads drained before next half overwrites
  }
}

// ---------------------------------------------------------------------------
// Pass 2: out = (P @ supT^T) / lsum[row], K = 8192 (bf16).
// Round-6 proven: 128.6 us, MfmaUtil 48%, ~structural floor for 2-block
// overlap at this geometry.
// ---------------------------------------------------------------------------
__global__ __launch_bounds__(256, 2)
void pv(const unsigned short* __restrict__ P,
        const unsigned short* __restrict__ supT,
        const float* __restrict__ lsum,
        float* __restrict__ out) {
  __shared__ __align__(16) unsigned short As[2][128 * 64];
  __shared__ __align__(16) unsigned short Bs[2][128 * 64];
  const int tid = threadIdx.x;
  const int i0 = blockIdx.x * 128;
  const int n0 = blockIdx.y * 128;

  f32x4 acc[4][4];
#pragma unroll
  for (int a = 0; a < 4; a++)
#pragma unroll
    for (int b = 0; b < 4; b++) acc[a][b] = (f32x4){0.f, 0.f, 0.f, 0.f};

  mfma_core_db<NQ, NQ, NQ>(P, supT, i0, n0, tid, As[0], As[1], Bs[0], Bs[1],
                           acc);

  const int lane = tid & 63;
  const int w = tid >> 6;
  const int wr = (w >> 1) * 64, wc = (w & 1) * 64;
  const int l16 = lane & 15, lq = lane >> 4;
#pragma unroll
  for (int ti = 0; ti < 4; ti++) {
#pragma unroll
    for (int r = 0; r < 4; r++) {
      const int row = i0 + wr + 16 * ti + lq * 4 + r;
      const float linv = 1.f / lsum[row];
#pragma unroll
      for (int tj = 0; tj < 4; tj++) {
        const int col = n0 + wc + 16 * tj + l16;
        out[(size_t)row * DD + col] = acc[ti][tj][r] * linv;
      }
    }
  }
}

// ---------------------------------------------------------------------------
// Fallback fp32 path — only if ws_size is too small.
// ---------------------------------------------------------------------------
#define BM 64
#define BN 64
#define BK 16

__global__ __launch_bounds__(256, 4)
void gemm64(const float* __restrict__ A, const float* __restrict__ B,
            float* __restrict__ C, int M, int N, int K) {
  __shared__ __align__(16) float As[BK][BM + 4];
  __shared__ __align__(16) float Bs[BK][BN + 4];
  const int tid = threadIdx.x;
  const int tx = tid & 15;
  const int ty = tid >> 4;
  const int row0 = blockIdx.y * BM;
  const int col0 = blockIdx.x * BN;
  float acc[4][4] = {};
  for (int k0 = 0; k0 < K; k0 += BK) {
    {
      const int r = tid >> 2;
      const int c4 = (tid & 3) * 4;
      const float4 v = *(const float4*)&A[(size_t)(row0 + r) * K + k0 + c4];
      As[c4 + 0][r] = v.x; As[c4 + 1][r] = v.y;
      As[c4 + 2][r] = v.z; As[c4 + 3][r] = v.w;
    }
    {
      const int r = tid >> 4;
      const int c4 = (tid & 15) * 4;
      *(float4*)&Bs[r][c4] = *(const float4*)&B[(size_t)(k0 + r) * N + col0 + c4];
    }
    __syncthreads();
#pragma unroll
    for (int k = 0; k < BK; k++) {
      const float4 a = *(const float4*)&As[k][4 * ty];
      const float4 b = *(const float4*)&Bs[k][4 * tx];
      const float av[4] = {a.x, a.y, a.z, a.w};
      const float bv[4] = {b.x, b.y, b.z, b.w};
#pragma unroll
      for (int i = 0; i < 4; i++)
#pragma unroll
        for (int j = 0; j < 4; j++)
          acc[i][j] += av[i] * bv[j];
    }
    __syncthreads();
  }
#pragma unroll
  for (int i = 0; i < 4; i++) {
    float4 o = {acc[i][0], acc[i][1], acc[i][2], acc[i][3]};
    *(float4*)&C[(size_t)(row0 + 4 * ty + i) * N + col0 + 4 * tx] = o;
  }
}

#define IT 32
#define JT 128
#define KC 32
#define CC 128
#define NCH (DD / CC)

__global__ __launch_bounds__(256, 1)
void fused_attn(const float* __restrict__ xi, const float* __restrict__ sup,
                float* __restrict__ out) {
  __shared__ __align__(16) float XiI[KC][IT + 4];
  __shared__ __align__(16) float XiJ[KC][JT + 4];
  __shared__ __align__(16) float Ps[JT][IT + 4];
  __shared__ __align__(16) float Vs[JT][CC + 4];
  __shared__ float lsum[IT];
  const int tid = threadIdx.x;
  const int i0 = blockIdx.x * IT;
  const int ry = tid >> 5;
  const int cx = tid & 31;
  if (tid < IT) lsum[tid] = 0.f;
  float oacc[NCH][4][4];
#pragma unroll
  for (int ch = 0; ch < NCH; ch++)
#pragma unroll
    for (int i = 0; i < 4; i++)
#pragma unroll
      for (int j = 0; j < 4; j++) oacc[ch][i][j] = 0.f;
  for (int j0 = 0; j0 < NQ; j0 += JT) {
    float sacc[4][4] = {};
    for (int kc = 0; kc < DD; kc += KC) {
      __syncthreads();
      {
        const int r = tid >> 3;
        const int k4 = (tid & 7) * 4;
        const float4 v = *(const float4*)&xi[(size_t)(i0 + r) * DD + kc + k4];
        XiI[k4 + 0][r] = v.x; XiI[k4 + 1][r] = v.y;
        XiI[k4 + 2][r] = v.z; XiI[k4 + 3][r] = v.w;
      }
#pragma unroll
      for (int i = 0; i < 4; i++) {
        const int idx = tid + i * 256;
        const int r = idx >> 3;
        const int k4 = (idx & 7) * 4;
        const float4 v = *(const float4*)&xi[(size_t)(j0 + r) * DD + kc + k4];
        XiJ[k4 + 0][r] = v.x; XiJ[k4 + 1][r] = v.y;
        XiJ[k4 + 2][r] = v.z; XiJ[k4 + 3][r] = v.w;
      }
      __syncthreads();
#pragma unroll
      for (int k = 0; k < KC; k++) {
        const float4 a = *(const float4*)&XiI[k][4 * ry];
        const float4 b = *(const float4*)&XiJ[k][4 * cx];
        const float av[4] = {a.x, a.y, a.z, a.w};
        const float bv[4] = {b.x, b.y, b.z, b.w};
#pragma unroll
        for (int i = 0; i < 4; i++)
#pragma unroll
          for (int j = 0; j < 4; j++)
            sacc[i][j] += av[i] * bv[j];
      }
    }
    __syncthreads();
    float rsv[4] = {0.f, 0.f, 0.f, 0.f};
#pragma unroll
    for (int i = 0; i < 4; i++)
#pragma unroll
      for (int j = 0; j < 4; j++) {
        const float p = __expf(sacc[i][j]);
        Ps[4 * cx + j][4 * ry + i] = p;
        rsv[i] += p;
      }
#pragma unroll
    for (int m = 16; m >= 1; m >>= 1)
#pragma unroll
      for (int i = 0; i < 4; i++) rsv[i] += __shfl_xor(rsv[i], m);
    if (cx == 0) {
#pragma unroll
      for (int i = 0; i < 4; i++) lsum[4 * ry + i] += rsv[i];
    }
    for (int ch = 0; ch < NCH; ch++) {
      __syncthreads();
#pragma unroll
      for (int i = 0; i < 16; i++) {
        const int idx = tid + i * 256;
        const int r = idx >> 5;
        const int c4 = (idx & 31) * 4;
        *(float4*)&Vs[r][c4] =
            *(const float4*)&sup[(size_t)(j0 + r) * DD + ch * CC + c4];
      }
      __syncthreads();
#pragma unroll 4
      for (int jp = 0; jp < JT; jp++) {
        const float4 p = *(const float4*)&Ps[jp][4 * ry];
        const float4 v = *(const float4*)&Vs[jp][4 * cx];
        const float pvv[4] = {p.x, p.y, p.z, p.w};
        const float vv[4] = {v.x, v.y, v.z, v.w};
#pragma unroll
        for (int i = 0; i < 4; i++)
#pragma unroll
          for (int j = 0; j < 4; j++)
            oacc[ch][i][j] += pvv[i] * vv[j];
      }
    }
  }
  __syncthreads();
  float linv[4];
#pragma unroll
  for (int i = 0; i < 4; i++) linv[i] = 1.f / lsum[4 * ry + i];
#pragma unroll
  for (int ch = 0; ch < NCH; ch++)
#pragma unroll
    for (int i = 0; i < 4; i++) {
      float4 o = {oacc[ch][i][0] * linv[i], oacc[ch][i][1] * linv[i],
                  oacc[ch][i][2] * linv[i], oacc[ch][i][3] * linv[i]};
      *(float4*)&out[(size_t)(i0 + 4 * ry + i) * DD + ch * CC + 4 * cx] = o;
    }
}

// ---------------------------------------------------------------------------
// Launch. ws layout (MFMA path, NEED = 152 MB + 32 KB):
//   P    : [0, 128MB)    bf16 [8192][8192]
//   xif  : [128,136MB)   e4m3 [8192][1024] (= fp8(16*xi))
//   supT : [136,152MB)   bf16 [1024][8192]
//   lsum : [152MB,+32KB) fp32 [8192]  (zeroed, filled by qk_fp8 atomics)
//   transients (consumed before P is written, alias the P region):
//     xb [0,16MB) bf16 [8192][1024];  tiT [16,18MB);  wT [18,20MB)
// NOTE: reference uses transferi for BOTH projections; transferj unused.
// ---------------------------------------------------------------------------
extern "C" void kernel_launch(void* const* d_in, const int* in_sizes, int n_in,
                              void* d_out, int out_size, void* d_ws, size_t ws_size,
                              hipStream_t stream) {
  const float* x  = (const float*)d_in[0];
  const float* wt = (const float*)d_in[1];
  const float* ti = (const float*)d_in[2];
  float* out = (float*)d_out;

  char* ws = (char*)d_ws;
  const size_t MB = 1024 * 1024;
  const size_t NEED = 152 * MB + NQ * sizeof(float);

  if (ws_size >= NEED) {
    unsigned short* P    = (unsigned short*)ws;
    unsigned char*  xif  = (unsigned char*)(ws + 128 * MB);
    unsigned short* supT = (unsigned short*)(ws + 136 * MB);
    float* lsum          = (float*)(ws + 152 * MB);
    unsigned short* xb   = (unsigned short*)ws;             // transient in P
    unsigned short* tiT  = (unsigned short*)(ws + 16 * MB); // transient in P
    unsigned short* wT   = (unsigned short*)(ws + 18 * MB); // transient in P

    const int n4 = NQ * DD / 4;
    zero_f32<<<NQ / 256, 256, 0, stream>>>(lsum, NQ);
    f32_to_bf16<<<(n4 + 255) / 256, 256, 0, stream>>>(x, xb, n4);
    transpose_cvt<<<dim3(32, 32), 256, 0, stream>>>(ti, tiT, DD, DD);
    transpose_cvt<<<dim3(32, 32), 256, 0, stream>>>(wt, wT, DD, DD);

    // xif[m][n] = e4m3(16 * sum_k xb[m][k]*ti[k][n])
    proj_gemm<DD, true><<<dim3(DD / 128, NQ / 128), 256, 0, stream>>>(xb, tiT, xif);
    // supT[n][m] = bf16(sum_k W[k][n]*x[m][k])
    proj_gemm<NQ, false><<<dim3(NQ / 128, DD / 128), 256, 0, stream>>>(wT, xb, supT);

    qk_fp8<<<dim3(NQ / 256, NQ / 128), 256, 0, stream>>>(xif, P, lsum);
    pv<<<dim3(NQ / 128, DD / 128), 256, 0, stream>>>(P, supT, lsum, out);
  } else {
    float* xi32  = (float*)ws;
    float* sup32 = (float*)(ws + 32 * MB);
    dim3 ggrid(DD / BN, NQ / BM);
    gemm64<<<ggrid, 256, 0, stream>>>(x, ti, xi32, NQ, DD, DD);
    gemm64<<<ggrid, 256, 0, stream>>>(x, wt, sup32, NQ, DD, DD);
    fused_attn<<<NQ / IT, 256, 0, stream>>>(xi32, sup32, out);
  }
}

// Round 10
// 358.005 us; speedup vs baseline: 1.0169x; 1.0169x over previous
//
#include <hip/hip_runtime.h>
#include <hip/hip_bf16.h>
#include <cstddef>

// Problem constants (match reference).
#define NQ 8192
#define DD 1024

typedef __attribute__((ext_vector_type(8))) short s8v;     // 8 bf16 (4 VGPR)
typedef __attribute__((ext_vector_type(8))) int i8v;       // 32 fp8 bytes (8 VGPR)
typedef __attribute__((ext_vector_type(4))) float f32x4;   // 16x16 C/D frag
typedef __attribute__((ext_vector_type(16))) float f32x16; // 32x32 C/D frag

typedef const __attribute__((address_space(1))) unsigned int* gptr_t;
typedef __attribute__((address_space(3))) unsigned int* lptr_t;

#define SCALE_1_16 0x7B7B7B7Bu  // E8M0 123 = 2^-4 in every byte

__device__ inline unsigned short f2bf(float f) {
  union { float f; unsigned u; } v; v.f = f;
  unsigned r = (v.u + 0x7FFFu + ((v.u >> 16) & 1u)) >> 16;  // RNE
  return (unsigned short)r;
}
__device__ inline float bits2f(unsigned u) {
  union { unsigned u; float f; } v; v.u = u;
  return v.f;
}

// f32 -> OCP e4m3 bits, RNE, clamp to +-448.
__device__ inline unsigned char f2e4m3(float x) {
  union { float f; unsigned u; } v; v.f = x;
  const unsigned s = (v.u >> 31) << 7;
  unsigned au = v.u & 0x7FFFFFFFu;
  if (au > 0x43E00000u) au = 0x43E00000u;  // clamp |x| to 448.0
  if (au >= 0x3C800000u) {                 // |x| >= 2^-6: e4m3 normal
    const unsigned rounded = au + 0x7FFFFu + ((au >> 20) & 1u);  // RNE @ 3 mant
    const unsigned e8 = ((rounded >> 23) & 0xFF) - 120u;         // -127+7
    const unsigned m8 = (rounded >> 20) & 7u;
    return (unsigned char)(s | (e8 << 3) | m8);
  } else {                                 // subnormal
    union { unsigned u; float f; } a; a.u = au;
    const unsigned q = (unsigned)rintf(a.f * 512.0f);  // 0..8
    return (unsigned char)(s | q);
  }
}

// Register-only combine of two 16-B LDS loads into one fp8 MFMA operand.
__device__ inline i8v make_i8v(int4 a, int4 b) {
  i8v v;
  v[0] = a.x; v[1] = a.y; v[2] = a.z; v[3] = a.w;
  v[4] = b.x; v[5] = b.y; v[6] = b.z; v[7] = b.w;
  return v;
}

// ---------------------------------------------------------------------------
// Double-buffered m97-style bf16 MFMA loop: C(128x128) += A(128xK) @ B(128xK)^T.
// stage(t+1) ISSUED before compute(t); one vmcnt(0)+barrier per K-step.
// Proven round-6: pv 143 -> 128.6 us, MfmaUtil 48%.
// XOR-swizzled 16-B chunks, 0 bank conflicts (verified round-0).
// ---------------------------------------------------------------------------
template <int KDIM, int ASTR, int BSTR>
__device__ inline void mfma_core_db(const unsigned short* __restrict__ A,
                                    const unsigned short* __restrict__ B,
                                    int i0, int j0, int tid,
                                    unsigned short* __restrict__ As0,
                                    unsigned short* __restrict__ As1,
                                    unsigned short* __restrict__ Bs0,
                                    unsigned short* __restrict__ Bs1,
                                    f32x4 (&acc)[4][4]) {
  const int lane = tid & 63;
  const int w = tid >> 6;
  const int wr = (w >> 1) * 64;
  const int wc = (w & 1) * 64;
  const int l16 = lane & 15;
  const int lq = lane >> 4;
  const int srow = lane >> 3;                          // 0..7
  const int scol = (((lane & 7) ^ (srow & 7)) * 8);    // swizzled 16-B chunk

  auto stage = [&](unsigned short* dA, unsigned short* dB, int kk) {
#pragma unroll
    for (int t = 0; t < 4; t++) {
      const int r0 = w * 32 + t * 8;
      const unsigned short* g = &A[(size_t)(i0 + r0 + srow) * ASTR + kk + scol];
      __builtin_amdgcn_global_load_lds((gptr_t)(const void*)g,
                                       (lptr_t)(void*)&dA[r0 * 64], 16, 0, 0);
    }
#pragma unroll
    for (int t = 0; t < 4; t++) {
      const int r0 = w * 32 + t * 8;
      const unsigned short* g = &B[(size_t)(j0 + r0 + srow) * BSTR + kk + scol];
      __builtin_amdgcn_global_load_lds((gptr_t)(const void*)g,
                                       (lptr_t)(void*)&dB[r0 * 64], 16, 0, 0);
    }
  };

  stage(As0, Bs0, 0);
  asm volatile("s_waitcnt vmcnt(0)" ::: "memory");
  __syncthreads();

  const int h = l16 & 7;
  unsigned short* curA = As0;
  unsigned short* curB = Bs0;
  unsigned short* nxtA = As1;
  unsigned short* nxtB = Bs1;
#pragma unroll 1
  for (int t = 0; t < KDIM / 64; t++) {
    if (t < KDIM / 64 - 1) stage(nxtA, nxtB, (t + 1) * 64);  // fly over compute
    s8v af[4][2], bf[4][2];
#pragma unroll
    for (int q = 0; q < 4; q++)
#pragma unroll
      for (int s = 0; s < 2; s++) {
        const int ch = ((s * 4 + lq) ^ h) * 8;  // swizzled chunk offset
        af[q][s] = *(const s8v*)&curA[(wr + 16 * q + l16) * 64 + ch];
        bf[q][s] = *(const s8v*)&curB[(wc + 16 * q + l16) * 64 + ch];
      }
#pragma unroll
    for (int s = 0; s < 2; s++)
#pragma unroll
      for (int a = 0; a < 4; a++)
#pragma unroll
        for (int b = 0; b < 4; b++)
          acc[a][b] = __builtin_amdgcn_mfma_f32_16x16x32_bf16(
              af[a][s], bf[b][s], acc[a][b], 0, 0, 0);
    asm volatile("s_waitcnt vmcnt(0)" ::: "memory");  // next buffer landed
    __syncthreads();
    unsigned short* tA = curA; curA = nxtA; nxtA = tA;
    unsigned short* tB = curB; curB = nxtB; nxtB = tB;
  }
}

// ---------------------------------------------------------------------------
// fp32 -> bf16 elementwise.
// ---------------------------------------------------------------------------
__global__ void f32_to_bf16(const float* __restrict__ in,
                            unsigned short* __restrict__ out, int n4) {
  int i = (blockIdx.x * blockDim.x + threadIdx.x);
  if (i < n4) {
    const float4 v = *(const float4*)&in[i * 4];
    ushort4 o;
    o.x = f2bf(v.x); o.y = f2bf(v.y); o.z = f2bf(v.z); o.w = f2bf(v.w);
    *(ushort4*)&out[i * 4] = o;
  }
}

__global__ void zero_f32(float* __restrict__ p, int n) {
  const int i = blockIdx.x * blockDim.x + threadIdx.x;
  if (i < n) p[i] = 0.f;
}

// ---------------------------------------------------------------------------
// fp32 [R][C] -> bf16 [C][R] transpose+convert (32x32 LDS tiles).
// ---------------------------------------------------------------------------
__global__ void transpose_cvt(const float* __restrict__ in,
                              unsigned short* __restrict__ out, int R, int C) {
  __shared__ float t[32][33];
  const int bx = blockIdx.x;
  const int by = blockIdx.y;
  const int x = threadIdx.x & 31;
  const int y = threadIdx.x >> 5;
#pragma unroll
  for (int i = 0; i < 32; i += 8)
    t[y + i][x] = in[(size_t)(by * 32 + y + i) * C + bx * 32 + x];
  __syncthreads();
#pragma unroll
  for (int i = 0; i < 32; i += 8)
    out[(size_t)(bx * 32 + y + i) * R + by * 32 + x] = f2bf(t[x][y + i]);
}

// ---------------------------------------------------------------------------
// Projection GEMM: C[m][n] = sum_k A[m][k] * BT[n][k], bf16 in, K=1024.
// FP8OUT=true writes e4m3(16*value) for the MX qk pass (8 MB output — byte
// stores fine at this size, verified rounds 0-2; xif is L3-resident so no
// partial-sector amplification).
// ---------------------------------------------------------------------------
template <int NST, bool FP8OUT>
__global__ __launch_bounds__(256, 2)
void proj_gemm(const unsigned short* __restrict__ A,
               const unsigned short* __restrict__ BT,
               void* __restrict__ Cout) {
  __shared__ __align__(16) unsigned short As[2][128 * 64];
  __shared__ __align__(16) unsigned short Bs[2][128 * 64];
  const int tid = threadIdx.x;
  const int m0 = blockIdx.y * 128;
  const int n0 = blockIdx.x * 128;

  f32x4 acc[4][4];
#pragma unroll
  for (int a = 0; a < 4; a++)
#pragma unroll
    for (int b = 0; b < 4; b++) acc[a][b] = (f32x4){0.f, 0.f, 0.f, 0.f};

  mfma_core_db<DD, DD, DD>(A, BT, m0, n0, tid, As[0], As[1], Bs[0], Bs[1], acc);

  const int lane = tid & 63;
  const int w = tid >> 6;
  const int wr = (w >> 1) * 64, wc = (w & 1) * 64;
  const int l16 = lane & 15, lq = lane >> 4;
#pragma unroll
  for (int ti = 0; ti < 4; ti++)
#pragma unroll
    for (int r = 0; r < 4; r++) {
      const int row = m0 + wr + 16 * ti + lq * 4 + r;
#pragma unroll
      for (int tj = 0; tj < 4; tj++) {
        const int col = n0 + wc + 16 * tj + l16;
        if (FP8OUT) {
          ((unsigned char*)Cout)[(size_t)row * NST + col] =
              f2e4m3(acc[ti][tj][r] * 16.f);
        } else {
          ((unsigned short*)Cout)[(size_t)row * NST + col] = f2bf(acc[ti][tj][r]);
        }
      }
    }
}

// ---------------------------------------------------------------------------
// Pass 1: P = exp(xi @ xi^T) via MX-scaled fp8 MFMA.
// xif holds e4m3(16*xi); both MFMA scales = 2^-4 undo the pre-scaling.
// 128x128 tile, 4 waves, each 64x64 = 2x2 of mfma_scale_f32_32x32x64_f8f6f4.
//
// Round-7 proven form (353.3 us total; round-9's 128x256 widening regressed
// +11 us — occupancy 3->2 and serialized epilogue halves outweighed the LDS
// byte cut; reverted).  LDS OVERLAY: staging dbuf (32 KB), lsums[128][65]
// (33.3 KB) and the bf16 out-tile (32 KB) time-share one 33.3 KB region ->
// 3 blocks/CU with the double buffer.  P written via LDS tile then 16-B
// dwordx4 (256-B segments/row).
// ---------------------------------------------------------------------------
__global__ __launch_bounds__(256, 3)
void qk_fp8(const unsigned char* __restrict__ xif,  // [8192][1024] e4m3(16*xi)
            unsigned short* __restrict__ P,         // [8192][8192] bf16 bits
            float* __restrict__ lsum) {             // [8192] fp32 (pre-zeroed)
  __shared__ __align__(16) unsigned char smem[128 * 65 * 4];  // 33.3 KB overlay
  unsigned char* AsF0 = smem;                 // 8 KB
  unsigned char* BsF0 = smem + 8192;          // 8 KB
  unsigned char* AsF1 = smem + 16384;         // 8 KB
  unsigned char* BsF1 = smem + 24576;         // 8 KB
  const int tid = threadIdx.x;
  const int lane = tid & 63;
  const int w = tid >> 6;
  const int i0 = blockIdx.y * 128;
  const int j0 = blockIdx.x * 128;

  f32x16 acc[2][2];
#pragma unroll
  for (int a = 0; a < 2; a++)
#pragma unroll
    for (int b = 0; b < 2; b++)
#pragma unroll
      for (int r = 0; r < 16; r++) acc[a][b][r] = 0.f;

  const int srow = lane >> 2;  // 0..15: row within 16-row staging group
  const int slot = lane & 3;   // 16-B chunk slot within the row
  const int kb = lane >> 5;    // frag k-block (0/1)
  const int l31 = lane & 31;

  auto stage = [&](unsigned char* dA, unsigned char* dB, int kk) {
#pragma unroll
    for (int t = 0; t < 2; t++) {
      const int r = w * 32 + t * 16 + srow;
      const int c = slot ^ ((r >> 1) & 3);  // logical chunk for this slot
      const unsigned char* ga = &xif[(size_t)(i0 + r) * DD + kk + c * 16];
      const unsigned char* gb = &xif[(size_t)(j0 + r) * DD + kk + c * 16];
      __builtin_amdgcn_global_load_lds((gptr_t)(const void*)ga,
                                       (lptr_t)(void*)&dA[(w * 32 + t * 16) * 64],
                                       16, 0, 0);
      __builtin_amdgcn_global_load_lds((gptr_t)(const void*)gb,
                                       (lptr_t)(void*)&dB[(w * 32 + t * 16) * 64],
                                       16, 0, 0);
    }
  };

  stage(AsF0, BsF0, 0);
  asm volatile("s_waitcnt vmcnt(0)" ::: "memory");
  __syncthreads();

  unsigned char* curA = AsF0;
  unsigned char* curB = BsF0;
  unsigned char* nxtA = AsF1;
  unsigned char* nxtB = BsF1;
#pragma unroll 1
  for (int t = 0; t < DD / 64; t++) {
    if (t < DD / 64 - 1) stage(nxtA, nxtB, (t + 1) * 64);  // fly over compute

    i8v af[2], bf[2];
#pragma unroll
    for (int mi = 0; mi < 2; mi++) {
      const int ar = (w >> 1) * 64 + mi * 32 + l31;
      const int sw = (ar >> 1) & 3;
      const int4 q0 = *(const int4*)&curA[ar * 64 + ((2 * kb + 0) ^ sw) * 16];
      const int4 q1 = *(const int4*)&curA[ar * 64 + ((2 * kb + 1) ^ sw) * 16];
      af[mi] = make_i8v(q0, q1);
    }
#pragma unroll
    for (int nj = 0; nj < 2; nj++) {
      const int br = (w & 1) * 64 + nj * 32 + l31;
      const int sw = (br >> 1) & 3;
      const int4 q0 = *(const int4*)&curB[br * 64 + ((2 * kb + 0) ^ sw) * 16];
      const int4 q1 = *(const int4*)&curB[br * 64 + ((2 * kb + 1) ^ sw) * 16];
      bf[nj] = make_i8v(q0, q1);
    }
#pragma unroll
    for (int mi = 0; mi < 2; mi++)
#pragma unroll
      for (int nj = 0; nj < 2; nj++)
        acc[mi][nj] = __builtin_amdgcn_mfma_scale_f32_32x32x64_f8f6f4(
            af[mi], bf[nj], acc[mi][nj], 0 /*cbsz: fp8*/, 0 /*blgp: fp8*/,
            0, SCALE_1_16, 0, SCALE_1_16);

    asm volatile("s_waitcnt vmcnt(0)" ::: "memory");
    __syncthreads();
    unsigned char* tA = curA; curA = nxtA; nxtA = tA;
    unsigned char* tB = curB; curB = nxtB; nxtB = tB;
  }
  // Loop ends with a full barrier: smem staging region is dead from here.

  // exp into registers (acc dies here; compiler reuses).
  // 32x32 C layout: row = (reg&3) + 8*(reg>>2) + 4*(lane>>5), col = lane&31.
  float ex0[2][16], ex1[2][16];
#pragma unroll
  for (int mi = 0; mi < 2; mi++)
#pragma unroll
    for (int reg = 0; reg < 16; reg++) {
      ex0[mi][reg] = __expf(acc[mi][0][reg]);
      ex1[mi][reg] = __expf(acc[mi][1][reg]);
    }

  const int mbase = (w >> 1) * 64;
  const int nbase = (w & 1) * 64;
  const int rowoff = 4 * (lane >> 5);
  const int cslot = (w & 1) * 32 + l31;  // column slot: wave n-half x lane

  // Phase A: lsums partials in the overlay, reduce, one atomicAdd per row.
  float (*lsums)[65] = (float (*)[65])smem;  // 33.3 KB, padded stride
#pragma unroll
  for (int mi = 0; mi < 2; mi++)
#pragma unroll
    for (int r4 = 0; r4 < 4; r4++)
#pragma unroll
      for (int rr = 0; rr < 4; rr++) {
        const int reg = r4 * 4 + rr;
        const int rl = mbase + mi * 32 + rr + 8 * r4 + rowoff;
        lsums[rl][cslot] = ex0[mi][reg] + ex1[mi][reg];
      }
  __syncthreads();
  if (tid < 128) {
    float s = 0.f;
#pragma unroll
    for (int c = 0; c < 64; c++) s += lsums[tid][c];
    atomicAdd(&lsum[i0 + tid], s);
  }
  __syncthreads();  // lsums reads drained before tile overwrite

  // Phase B: bf16 tile in the overlay, then coalesced 256-B row stores.
  unsigned short* tile = (unsigned short*)smem;  // [128][128]
#pragma unroll
  for (int mi = 0; mi < 2; mi++)
#pragma unroll
    for (int r4 = 0; r4 < 4; r4++)
#pragma unroll
      for (int rr = 0; rr < 4; rr++) {
        const int reg = r4 * 4 + rr;
        const int rl = mbase + mi * 32 + rr + 8 * r4 + rowoff;
        tile[rl * 128 + nbase + l31]      = f2bf(ex0[mi][reg]);
        tile[rl * 128 + nbase + l31 + 32] = f2bf(ex1[mi][reg]);
      }
  __syncthreads();
  {
    const int rr2 = tid >> 4;       // 0..15: row within 16-row group
    const int ch = (tid & 15) * 8;  // 8 shorts = 16 B; 16 lanes = 256 B/row
#pragma unroll
    for (int q = 0; q < 8; q++) {
      const int row = rr2 + q * 16;
      const int4 v = *(const int4*)&tile[row * 128 + ch];
      *(int4*)&P[(size_t)(i0 + row) * NQ + j0 + ch] = v;
    }
  }
}

// ---------------------------------------------------------------------------
// Pass 2: out = (P @ supT^T) / lsum[row], K = 8192 (bf16).
// Round-6 proven: 128.6 us, MfmaUtil 48%, ~structural floor for 2-block
// overlap at this geometry.
// ---------------------------------------------------------------------------
__global__ __launch_bounds__(256, 2)
void pv(const unsigned short* __restrict__ P,
        const unsigned short* __restrict__ supT,
        const float* __restrict__ lsum,
        float* __restrict__ out) {
  __shared__ __align__(16) unsigned short As[2][128 * 64];
  __shared__ __align__(16) unsigned short Bs[2][128 * 64];
  const int tid = threadIdx.x;
  const int i0 = blockIdx.x * 128;
  const int n0 = blockIdx.y * 128;

  f32x4 acc[4][4];
#pragma unroll
  for (int a = 0; a < 4; a++)
#pragma unroll
    for (int b = 0; b < 4; b++) acc[a][b] = (f32x4){0.f, 0.f, 0.f, 0.f};

  mfma_core_db<NQ, NQ, NQ>(P, supT, i0, n0, tid, As[0], As[1], Bs[0], Bs[1],
                           acc);

  const int lane = tid & 63;
  const int w = tid >> 6;
  const int wr = (w >> 1) * 64, wc = (w & 1) * 64;
  const int l16 = lane & 15, lq = lane >> 4;
#pragma unroll
  for (int ti = 0; ti < 4; ti++) {
#pragma unroll
    for (int r = 0; r < 4; r++) {
      const int row = i0 + wr + 16 * ti + lq * 4 + r;
      const float linv = 1.f / lsum[row];
#pragma unroll
      for (int tj = 0; tj < 4; tj++) {
        const int col = n0 + wc + 16 * tj + l16;
        out[(size_t)row * DD + col] = acc[ti][tj][r] * linv;
      }
    }
  }
}

// ---------------------------------------------------------------------------
// Fallback fp32 path — only if ws_size is too small.
// ---------------------------------------------------------------------------
#define BM 64
#define BN 64
#define BK 16

__global__ __launch_bounds__(256, 4)
void gemm64(const float* __restrict__ A, const float* __restrict__ B,
            float* __restrict__ C, int M, int N, int K) {
  __shared__ __align__(16) float As[BK][BM + 4];
  __shared__ __align__(16) float Bs[BK][BN + 4];
  const int tid = threadIdx.x;
  const int tx = tid & 15;
  const int ty = tid >> 4;
  const int row0 = blockIdx.y * BM;
  const int col0 = blockIdx.x * BN;
  float acc[4][4] = {};
  for (int k0 = 0; k0 < K; k0 += BK) {
    {
      const int r = tid >> 2;
      const int c4 = (tid & 3) * 4;
      const float4 v = *(const float4*)&A[(size_t)(row0 + r) * K + k0 + c4];
      As[c4 + 0][r] = v.x; As[c4 + 1][r] = v.y;
      As[c4 + 2][r] = v.z; As[c4 + 3][r] = v.w;
    }
    {
      const int r = tid >> 4;
      const int c4 = (tid & 15) * 4;
      *(float4*)&Bs[r][c4] = *(const float4*)&B[(size_t)(k0 + r) * N + col0 + c4];
    }
    __syncthreads();
#pragma unroll
    for (int k = 0; k < BK; k++) {
      const float4 a = *(const float4*)&As[k][4 * ty];
      const float4 b = *(const float4*)&Bs[k][4 * tx];
      const float av[4] = {a.x, a.y, a.z, a.w};
      const float bv[4] = {b.x, b.y, b.z, b.w};
#pragma unroll
      for (int i = 0; i < 4; i++)
#pragma unroll
        for (int j = 0; j < 4; j++)
          acc[i][j] += av[i] * bv[j];
    }
    __syncthreads();
  }
#pragma unroll
  for (int i = 0; i < 4; i++) {
    float4 o = {acc[i][0], acc[i][1], acc[i][2], acc[i][3]};
    *(float4*)&C[(size_t)(row0 + 4 * ty + i) * N + col0 + 4 * tx] = o;
  }
}

#define IT 32
#define JT 128
#define KC 32
#define CC 128
#define NCH (DD / CC)

__global__ __launch_bounds__(256, 1)
void fused_attn(const float* __restrict__ xi, const float* __restrict__ sup,
                float* __restrict__ out) {
  __shared__ __align__(16) float XiI[KC][IT + 4];
  __shared__ __align__(16) float XiJ[KC][JT + 4];
  __shared__ __align__(16) float Ps[JT][IT + 4];
  __shared__ __align__(16) float Vs[JT][CC + 4];
  __shared__ float lsum[IT];
  const int tid = threadIdx.x;
  const int i0 = blockIdx.x * IT;
  const int ry = tid >> 5;
  const int cx = tid & 31;
  if (tid < IT) lsum[tid] = 0.f;
  float oacc[NCH][4][4];
#pragma unroll
  for (int ch = 0; ch < NCH; ch++)
#pragma unroll
    for (int i = 0; i < 4; i++)
#pragma unroll
      for (int j = 0; j < 4; j++) oacc[ch][i][j] = 0.f;
  for (int j0 = 0; j0 < NQ; j0 += JT) {
    float sacc[4][4] = {};
    for (int kc = 0; kc < DD; kc += KC) {
      __syncthreads();
      {
        const int r = tid >> 3;
        const int k4 = (tid & 7) * 4;
        const float4 v = *(const float4*)&xi[(size_t)(i0 + r) * DD + kc + k4];
        XiI[k4 + 0][r] = v.x; XiI[k4 + 1][r] = v.y;
        XiI[k4 + 2][r] = v.z; XiI[k4 + 3][r] = v.w;
      }
#pragma unroll
      for (int i = 0; i < 4; i++) {
        const int idx = tid + i * 256;
        const int r = idx >> 3;
        const int k4 = (idx & 7) * 4;
        const float4 v = *(const float4*)&xi[(size_t)(j0 + r) * DD + kc + k4];
        XiJ[k4 + 0][r] = v.x; XiJ[k4 + 1][r] = v.y;
        XiJ[k4 + 2][r] = v.z; XiJ[k4 + 3][r] = v.w;
      }
      __syncthreads();
#pragma unroll
      for (int k = 0; k < KC; k++) {
        const float4 a = *(const float4*)&XiI[k][4 * ry];
        const float4 b = *(const float4*)&XiJ[k][4 * cx];
        const float av[4] = {a.x, a.y, a.z, a.w};
        const float bv[4] = {b.x, b.y, b.z, b.w};
#pragma unroll
        for (int i = 0; i < 4; i++)
#pragma unroll
          for (int j = 0; j < 4; j++)
            sacc[i][j] += av[i] * bv[j];
      }
    }
    __syncthreads();
    float rsv[4] = {0.f, 0.f, 0.f, 0.f};
#pragma unroll
    for (int i = 0; i < 4; i++)
#pragma unroll
      for (int j = 0; j < 4; j++) {
        const float p = __expf(sacc[i][j]);
        Ps[4 * cx + j][4 * ry + i] = p;
        rsv[i] += p;
      }
#pragma unroll
    for (int m = 16; m >= 1; m >>= 1)
#pragma unroll
      for (int i = 0; i < 4; i++) rsv[i] += __shfl_xor(rsv[i], m);
    if (cx == 0) {
#pragma unroll
      for (int i = 0; i < 4; i++) lsum[4 * ry + i] += rsv[i];
    }
    for (int ch = 0; ch < NCH; ch++) {
      __syncthreads();
#pragma unroll
      for (int i = 0; i < 16; i++) {
        const int idx = tid + i * 256;
        const int r = idx >> 5;
        const int c4 = (idx & 31) * 4;
        *(float4*)&Vs[r][c4] =
            *(const float4*)&sup[(size_t)(j0 + r) * DD + ch * CC + c4];
      }
      __syncthreads();
#pragma unroll 4
      for (int jp = 0; jp < JT; jp++) {
        const float4 p = *(const float4*)&Ps[jp][4 * ry];
        const float4 v = *(const float4*)&Vs[jp][4 * cx];
        const float pvv[4] = {p.x, p.y, p.z, p.w};
        const float vv[4] = {v.x, v.y, v.z, v.w};
#pragma unroll
        for (int i = 0; i < 4; i++)
#pragma unroll
          for (int j = 0; j < 4; j++)
            oacc[ch][i][j] += pvv[i] * vv[j];
      }
    }
  }
  __syncthreads();
  float linv[4];
#pragma unroll
  for (int i = 0; i < 4; i++) linv[i] = 1.f / lsum[4 * ry + i];
#pragma unroll
  for (int ch = 0; ch < NCH; ch++)
#pragma unroll
    for (int i = 0; i < 4; i++) {
      float4 o = {oacc[ch][i][0] * linv[i], oacc[ch][i][1] * linv[i],
                  oacc[ch][i][2] * linv[i], oacc[ch][i][3] * linv[i]};
      *(float4*)&out[(size_t)(i0 + 4 * ry + i) * DD + ch * CC + 4 * cx] = o;
    }
}

// ---------------------------------------------------------------------------
// Launch. ws layout (MFMA path, NEED = 152 MB + 32 KB):
//   P    : [0, 128MB)    bf16 [8192][8192]
//   xif  : [128,136MB)   e4m3 [8192][1024] (= fp8(16*xi))
//   supT : [136,152MB)   bf16 [1024][8192]
//   lsum : [152MB,+32KB) fp32 [8192]  (zeroed, filled by qk_fp8 atomics)
//   transients (consumed before P is written, alias the P region):
//     xb [0,16MB) bf16 [8192][1024];  tiT [16,18MB);  wT [18,20MB)
// NOTE: reference uses transferi for BOTH projections; transferj unused.
// ---------------------------------------------------------------------------
extern "C" void kernel_launch(void* const* d_in, const int* in_sizes, int n_in,
                              void* d_out, int out_size, void* d_ws, size_t ws_size,
                              hipStream_t stream) {
  const float* x  = (const float*)d_in[0];
  const float* wt = (const float*)d_in[1];
  const float* ti = (const float*)d_in[2];
  float* out = (float*)d_out;

  char* ws = (char*)d_ws;
  const size_t MB = 1024 * 1024;
  const size_t NEED = 152 * MB + NQ * sizeof(float);

  if (ws_size >= NEED) {
    unsigned short* P    = (unsigned short*)ws;
    unsigned char*  xif  = (unsigned char*)(ws + 128 * MB);
    unsigned short* supT = (unsigned short*)(ws + 136 * MB);
    float* lsum          = (float*)(ws + 152 * MB);
    unsigned short* xb   = (unsigned short*)ws;             // transient in P
    unsigned short* tiT  = (unsigned short*)(ws + 16 * MB); // transient in P
    unsigned short* wT   = (unsigned short*)(ws + 18 * MB); // transient in P

    const int n4 = NQ * DD / 4;
    zero_f32<<<NQ / 256, 256, 0, stream>>>(lsum, NQ);
    f32_to_bf16<<<(n4 + 255) / 256, 256, 0, stream>>>(x, xb, n4);
    transpose_cvt<<<dim3(32, 32), 256, 0, stream>>>(ti, tiT, DD, DD);
    transpose_cvt<<<dim3(32, 32), 256, 0, stream>>>(wt, wT, DD, DD);

    // xif[m][n] = e4m3(16 * sum_k xb[m][k]*ti[k][n])
    proj_gemm<DD, true><<<dim3(DD / 128, NQ / 128), 256, 0, stream>>>(xb, tiT, xif);
    // supT[n][m] = bf16(sum_k W[k][n]*x[m][k])
    proj_gemm<NQ, false><<<dim3(NQ / 128, DD / 128), 256, 0, stream>>>(wT, xb, supT);

    qk_fp8<<<dim3(NQ / 128, NQ / 128), 256, 0, stream>>>(xif, P, lsum);
    pv<<<dim3(NQ / 128, DD / 128), 256, 0, stream>>>(P, supT, lsum, out);
  } else {
    float* xi32  = (float*)ws;
    float* sup32 = (float*)(ws + 32 * MB);
    dim3 ggrid(DD / BN, NQ / BM);
    gemm64<<<ggrid, 256, 0, stream>>>(x, ti, xi32, NQ, DD, DD);
    gemm64<<<ggrid, 256, 0, stream>>>(x, wt, sup32, NQ, DD, DD);
    fused_attn<<<NQ / IT, 256, 0, stream>>>(xi32, sup32, out);
  }
}